// Round 1
// baseline (37.512 us; speedup 1.0000x reference)
//
#include <hip/hip_runtime.h>

// Gather per-pixel superpixel logits:
//   out[i, y, x, :] = logits[(i * N_SP + segments[i,y,x]) * WAY + :]
// Shapes: logits (16*512, 5) f32, segments (16, 512, 512) i32,
//         out (16, 512, 512, 5) f32.

constexpr int N_IMG        = 16;
constexpr int SIZE         = 512;
constexpr int N_SP         = 512;
constexpr int WAY          = 5;
constexpr int PIX_PER_IMG  = SIZE * SIZE;                 // 262144
constexpr int NPIX         = N_IMG * PIX_PER_IMG;         // 4194304
constexpr int PIX_PER_THR  = 4;                           // 4 pixels -> 5x float4 out
constexpr int NTHR_TOTAL   = NPIX / PIX_PER_THR;          // 1048576

__global__ __launch_bounds__(256) void gather5_kernel(
    const float* __restrict__ logits,
    const int*   __restrict__ seg,
    float*       __restrict__ out)
{
    const int t0     = blockIdx.x * blockDim.x + threadIdx.x;
    const int stride = gridDim.x * blockDim.x;

    for (int t = t0; t < NTHR_TOTAL; t += stride) {
        const int p0  = t * PIX_PER_THR;          // first pixel of this group
        // PIX_PER_IMG is a multiple of 4, so all 4 pixels share one image.
        const int img = p0 >> 18;                 // p0 / PIX_PER_IMG
        const float* __restrict__ lg = logits + img * (N_SP * WAY);

        // 16B coalesced segment load (p0*4 bytes is 16B aligned).
        const int4 s = *reinterpret_cast<const int4*>(seg + p0);
        const int ss[4] = { s.x, s.y, s.z, s.w };

        float v[PIX_PER_THR * WAY];
        #pragma unroll
        for (int i = 0; i < PIX_PER_THR; ++i) {
            const float* __restrict__ row = lg + ss[i] * WAY;
            #pragma unroll
            for (int w = 0; w < WAY; ++w)
                v[i * WAY + w] = row[w];          // L1/L2-resident gather (10 KB table)
        }

        // 80 B contiguous output per thread -> 5 aligned float4 stores.
        float4* __restrict__ o =
            reinterpret_cast<float4*>(out + (long long)p0 * WAY);
        #pragma unroll
        for (int q = 0; q < (PIX_PER_THR * WAY) / 4; ++q)
            o[q] = make_float4(v[q * 4 + 0], v[q * 4 + 1],
                               v[q * 4 + 2], v[q * 4 + 3]);
    }
}

extern "C" void kernel_launch(void* const* d_in, const int* in_sizes, int n_in,
                              void* d_out, int out_size, void* d_ws, size_t ws_size,
                              hipStream_t stream) {
    const float* logits = (const float*)d_in[0];
    const int*   seg    = (const int*)d_in[1];
    float*       out    = (float*)d_out;

    // G11: cap grid ~2048 blocks, grid-stride the rest (2 iters/thread here).
    const int block = 256;
    const int grid  = 2048;
    gather5_kernel<<<grid, block, 0, stream>>>(logits, seg, out);
}

// Round 2
// 35.989 us; speedup vs baseline: 1.0423x; 1.0423x over previous
//
#include <hip/hip_runtime.h>

// Gather per-pixel superpixel logits:
//   out[i, y, x, :] = logits[(i * N_SP + segments[i,y,x]) * WAY + :]
// Shapes: logits (16*512, 5) f32, segments (16, 512, 512) i32,
//         out (16, 512, 512, 5) f32.
//
// R1 -> R2: per-lane random gathers from global (even L1-resident) serialize
// on distinct cache lines in the TA/L1. Stage the 10 KB per-image table in
// LDS instead; random-bank ds_read_b32 is ~free (2-way conflict, m136).

constexpr int N_IMG          = 16;
constexpr int SIZE           = 512;
constexpr int N_SP           = 512;
constexpr int WAY            = 5;
constexpr int PIX_PER_IMG    = SIZE * SIZE;                  // 262144
constexpr int BLOCK          = 256;
constexpr int PIX_PER_THR    = 4;                            // 4 pixels -> 5x float4 out
constexpr int PIX_PER_BLOCK  = BLOCK * PIX_PER_THR;          // 1024
constexpr int BLOCKS_PER_IMG = PIX_PER_IMG / PIX_PER_BLOCK;  // 256
constexpr int TABLE_FLOATS   = N_SP * WAY;                   // 2560 (10 KB)

__global__ __launch_bounds__(BLOCK) void gather5_lds_kernel(
    const float* __restrict__ logits,
    const int*   __restrict__ seg,
    float*       __restrict__ out)
{
    __shared__ float tab[TABLE_FLOATS];

    // One image per block; 256 blocks per image, direct mapping (grid = 4096).
    const int img = blockIdx.x >> 8;  // blockIdx.x / BLOCKS_PER_IMG

    // Cooperative table load: 2560 floats = 1280 float2, 5 per thread, coalesced.
    {
        const float2* __restrict__ src =
            reinterpret_cast<const float2*>(logits + img * TABLE_FLOATS);
        float2* dst = reinterpret_cast<float2*>(tab);
        #pragma unroll
        for (int i = threadIdx.x; i < TABLE_FLOATS / 2; i += BLOCK)
            dst[i] = src[i];
    }
    __syncthreads();

    const int p0 = blockIdx.x * PIX_PER_BLOCK + threadIdx.x * PIX_PER_THR;

    // 16B coalesced segment load (lane-consecutive 16B chunks).
    const int4 s = *reinterpret_cast<const int4*>(seg + p0);
    const int ss[4] = { s.x, s.y, s.z, s.w };

    float v[PIX_PER_THR * WAY];
    #pragma unroll
    for (int i = 0; i < PIX_PER_THR; ++i) {
        const int base = ss[i] * WAY;
        #pragma unroll
        for (int w = 0; w < WAY; ++w)
            v[i * WAY + w] = tab[base + w];      // ds_read_b32, random banks
    }

    // 80 B contiguous output per thread -> 5 aligned float4 stores, coalesced.
    float4* __restrict__ o =
        reinterpret_cast<float4*>(out + (long long)p0 * WAY);
    #pragma unroll
    for (int q = 0; q < (PIX_PER_THR * WAY) / 4; ++q)
        o[q] = make_float4(v[q * 4 + 0], v[q * 4 + 1],
                           v[q * 4 + 2], v[q * 4 + 3]);
}

extern "C" void kernel_launch(void* const* d_in, const int* in_sizes, int n_in,
                              void* d_out, int out_size, void* d_ws, size_t ws_size,
                              hipStream_t stream) {
    const float* logits = (const float*)d_in[0];
    const int*   seg    = (const int*)d_in[1];
    float*       out    = (float*)d_out;

    const int grid = N_IMG * BLOCKS_PER_IMG;   // 4096 blocks, direct-mapped
    gather5_lds_kernel<<<grid, BLOCK, 0, stream>>>(logits, seg, out);
}

// Round 3
// 23.693 us; speedup vs baseline: 1.5832x; 1.5190x over previous
//
#include <hip/hip_runtime.h>

// Gather per-pixel superpixel logits:
//   out[i, y, x, :] = logits[(i * N_SP + segments[i,y,x]) * WAY + :]
//
// R2 -> R3: R1 (global gather) == R2 (LDS gather) ==> gather was never the
// bottleneck. The common sin: per-thread-contiguous 80 B output means every
// store instruction writes 16 B/lane at stride 80 B -> ~80 partial cache
// lines per wave-instruction (5x transaction amplification). Fix: transpose
// through LDS so each store instruction is 64 lanes x 16 B CONTIGUOUS,
// matching the 6.6 TB/s fill-kernel pattern.

constexpr int N_IMG          = 16;
constexpr int SIZE           = 512;
constexpr int N_SP           = 512;
constexpr int WAY            = 5;
constexpr int PIX_PER_IMG    = SIZE * SIZE;                  // 262144
constexpr int BLOCK          = 256;
constexpr int PIX_PER_THR    = 4;                            // 4 px * 5 way = 20 floats
constexpr int PIX_PER_BLOCK  = BLOCK * PIX_PER_THR;          // 1024
constexpr int BLOCKS_PER_IMG = PIX_PER_IMG / PIX_PER_BLOCK;  // 256
constexpr int TABLE_FLOATS   = N_SP * WAY;                   // 2560 (10 KB)
constexpr int F4_PER_BLOCK   = PIX_PER_BLOCK * WAY / 4;      // 1280 (20 KB stage)

__global__ __launch_bounds__(BLOCK) void gather5_tr_kernel(
    const float* __restrict__ logits,
    const int*   __restrict__ seg,
    float*       __restrict__ out)
{
    __shared__ float  tab[TABLE_FLOATS];      // 10 KB per-image logits table
    __shared__ float4 stage[F4_PER_BLOCK];    // 20 KB output-order staging

    const int img = blockIdx.x >> 8;          // blockIdx.x / BLOCKS_PER_IMG

    // Cooperative table load: 2560 floats = 1280 float2, coalesced.
    {
        const float2* __restrict__ src =
            reinterpret_cast<const float2*>(logits + img * TABLE_FLOATS);
        float2* dst = reinterpret_cast<float2*>(tab);
        #pragma unroll
        for (int i = threadIdx.x; i < TABLE_FLOATS / 2; i += BLOCK)
            dst[i] = src[i];
    }
    __syncthreads();

    // 16 B coalesced segment load; 4 pixels per thread.
    const int p0 = blockIdx.x * PIX_PER_BLOCK + threadIdx.x * PIX_PER_THR;
    const int4 s = *reinterpret_cast<const int4*>(seg + p0);
    const int ss[4] = { s.x, s.y, s.z, s.w };

    float v[PIX_PER_THR * WAY];
    #pragma unroll
    for (int i = 0; i < PIX_PER_THR; ++i) {
        const int base = ss[i] * WAY;
        #pragma unroll
        for (int w = 0; w < WAY; ++w)
            v[i * WAY + w] = tab[base + w];    // ds_read_b32, random banks (~free)
    }

    // Stage in OUTPUT order: thread owns local float4 slots [5*tid, 5*tid+5).
    // (8-way bank conflict on these writes; ~60 cy/wave, negligible.)
    #pragma unroll
    for (int j = 0; j < WAY; ++j)
        stage[WAY * threadIdx.x + j] =
            make_float4(v[4 * j + 0], v[4 * j + 1], v[4 * j + 2], v[4 * j + 3]);
    __syncthreads();

    // Fully coalesced stores: each instruction = 64 lanes x 16 B contiguous.
    float4* __restrict__ o =
        reinterpret_cast<float4*>(out) + (long long)blockIdx.x * F4_PER_BLOCK;
    #pragma unroll
    for (int q = 0; q < WAY; ++q)
        o[q * BLOCK + threadIdx.x] = stage[q * BLOCK + threadIdx.x];
}

extern "C" void kernel_launch(void* const* d_in, const int* in_sizes, int n_in,
                              void* d_out, int out_size, void* d_ws, size_t ws_size,
                              hipStream_t stream) {
    const float* logits = (const float*)d_in[0];
    const int*   seg    = (const int*)d_in[1];
    float*       out    = (float*)d_out;

    const int grid = N_IMG * BLOCKS_PER_IMG;   // 4096 blocks, direct-mapped
    gather5_tr_kernel<<<grid, BLOCK, 0, stream>>>(logits, seg, out);
}

// Round 4
// 22.408 us; speedup vs baseline: 1.6740x; 1.0573x over previous
//
#include <hip/hip_runtime.h>

// Gather per-pixel superpixel logits:
//   out[i, y, x, :] = logits[(i * N_SP + segments[i,y,x]) * WAY + :]
//
// R3 -> R4: stores are already coalesced via LDS transpose, but the staging
// round-trip (5x b128 write @8-way conflict + 5x b128 read + 2nd barrier +
// 20KB LDS) only exists to reorder outputs. Compute the output-order mapping
// directly instead: thread owns 5 float4s at coalesced positions q*256+tid;
// each float4 spans <=2 pixels, decomposed as p=f/5, way=f%5 (magic-mul).
// Segments staged in 4KB LDS; logits table in 10KB LDS; ONE barrier.

constexpr int N_IMG          = 16;
constexpr int SIZE           = 512;
constexpr int N_SP           = 512;
constexpr int WAY            = 5;
constexpr int PIX_PER_IMG    = SIZE * SIZE;                  // 262144
constexpr int BLOCK          = 256;
constexpr int PIX_PER_BLOCK  = 1024;                         // per block
constexpr int BLOCKS_PER_IMG = PIX_PER_IMG / PIX_PER_BLOCK;  // 256
constexpr int TABLE_FLOATS   = N_SP * WAY;                   // 2560 (10 KB)
constexpr int F4_PER_BLOCK   = PIX_PER_BLOCK * WAY / 4;      // 1280
constexpr int F4_PER_THR     = F4_PER_BLOCK / BLOCK;         // 5

__global__ __launch_bounds__(BLOCK) void gather5_direct_kernel(
    const float* __restrict__ logits,
    const int*   __restrict__ seg,
    float*       __restrict__ out)
{
    __shared__ float tab[TABLE_FLOATS];       // 10 KB per-image logits table
    __shared__ int   segl[PIX_PER_BLOCK + 1]; // 4 KB block's segment ids (+pad)

    const int img = blockIdx.x >> 8;          // blockIdx.x / BLOCKS_PER_IMG

    // Stage logits table: 1280 float2, 5 per thread, coalesced.
    {
        const float2* __restrict__ src =
            reinterpret_cast<const float2*>(logits + img * TABLE_FLOATS);
        float2* dst = reinterpret_cast<float2*>(tab);
        #pragma unroll
        for (int i = threadIdx.x; i < TABLE_FLOATS / 2; i += BLOCK)
            dst[i] = src[i];
    }
    // Stage segment ids: one int4 per thread, coalesced.
    {
        const int4 s = *reinterpret_cast<const int4*>(
            seg + blockIdx.x * PIX_PER_BLOCK + 4 * threadIdx.x);
        *reinterpret_cast<int4*>(&segl[4 * threadIdx.x]) = s;
        if (threadIdx.x == 0) segl[PIX_PER_BLOCK] = 0;  // pad: p+1 speculative read
    }
    __syncthreads();

    float4* __restrict__ o =
        reinterpret_cast<float4*>(out) + (long long)blockIdx.x * F4_PER_BLOCK;

    #pragma unroll
    for (int q = 0; q < F4_PER_THR; ++q) {
        const unsigned gl  = q * BLOCK + threadIdx.x;   // block-local f4 idx
        const unsigned f   = 4u * gl;                   // block-local float idx
        const unsigned p   = f / 5u;                    // local pixel (magic-mul)
        const unsigned off = f - 5u * p;                // 0..4

        const int s0 = segl[p];
        const int s1 = segl[p + 1];
        const int r0 = s0 * WAY;                        // row base, pixel p
        const int r1 = s1 * WAY - 5;                    // row base, pixel p+1 (w>=5)

        float4 x;
        float* xf = reinterpret_cast<float*>(&x);
        #pragma unroll
        for (int k = 0; k < 4; ++k) {
            const unsigned w = off + k;                 // 0..7
            const int idx = (w >= 5u ? r1 : r0) + (int)w;
            xf[k] = tab[idx];                           // ds_read_b32
        }
        o[gl] = x;                                      // coalesced 64x16B store
    }
}

extern "C" void kernel_launch(void* const* d_in, const int* in_sizes, int n_in,
                              void* d_out, int out_size, void* d_ws, size_t ws_size,
                              hipStream_t stream) {
    const float* logits = (const float*)d_in[0];
    const int*   seg    = (const int*)d_in[1];
    float*       out    = (float*)d_out;

    const int grid = N_IMG * BLOCKS_PER_IMG;   // 4096 blocks, direct-mapped
    gather5_direct_kernel<<<grid, BLOCK, 0, stream>>>(logits, seg, out);
}

// Round 5
// 20.916 us; speedup vs baseline: 1.7935x; 1.0714x over previous
//
#include <hip/hip_runtime.h>

// Gather per-pixel superpixel logits:
//   out[i, y, x, :] = logits[(i * N_SP + segments[i,y,x]) * WAY + :]
//
// R4 -> R5: stores coalesced, gather in LDS, one barrier -- still 4.5 TB/s
// vs 6.6 demonstrated. Remaining suspect: structural overhead ~ block count
// (4096 staging phases, 2 residency rounds at 8 blocks/CU). Double the tile:
// 2048 px/block, grid = 2048 = exactly one full-resident set (18 KB LDS x 8
// blocks = 144 KB <= 160). All staging loads issue upfront; one barrier;
// 10 coalesced float4 stores per thread.

constexpr int N_IMG          = 16;
constexpr int SIZE           = 512;
constexpr int N_SP           = 512;
constexpr int WAY            = 5;
constexpr int PIX_PER_IMG    = SIZE * SIZE;                  // 262144
constexpr int BLOCK          = 256;
constexpr int PIX_PER_BLOCK  = 2048;
constexpr int BLOCKS_PER_IMG = PIX_PER_IMG / PIX_PER_BLOCK;  // 128
constexpr int TABLE_FLOATS   = N_SP * WAY;                   // 2560 (10 KB)
constexpr int F4_PER_BLOCK   = PIX_PER_BLOCK * WAY / 4;      // 2560
constexpr int F4_PER_THR     = F4_PER_BLOCK / BLOCK;         // 10

__global__ __launch_bounds__(BLOCK) void gather5_direct2_kernel(
    const float* __restrict__ logits,
    const int*   __restrict__ seg,
    float*       __restrict__ out)
{
    __shared__ float tab[TABLE_FLOATS];        // 10 KB per-image logits table
    __shared__ int   segl[PIX_PER_BLOCK + 1];  // 8 KB block's segment ids (+pad)

    const int img = blockIdx.x >> 7;           // blockIdx.x / BLOCKS_PER_IMG

    // Issue ALL staging loads upfront (latencies overlap), then LDS-write.
    const float2* __restrict__ tsrc =
        reinterpret_cast<const float2*>(logits + img * TABLE_FLOATS);
    float2 t[TABLE_FLOATS / 2 / BLOCK];        // 5 x float2 per thread
    #pragma unroll
    for (int i = 0; i < TABLE_FLOATS / 2 / BLOCK; ++i)
        t[i] = tsrc[i * BLOCK + threadIdx.x];

    const int4* __restrict__ ssrc = reinterpret_cast<const int4*>(
        seg + blockIdx.x * PIX_PER_BLOCK);
    const int4 s0 = ssrc[threadIdx.x];                 // pixels [0, 1024)
    const int4 s1 = ssrc[threadIdx.x + BLOCK];         // pixels [1024, 2048)

    {
        float2* dst = reinterpret_cast<float2*>(tab);
        #pragma unroll
        for (int i = 0; i < TABLE_FLOATS / 2 / BLOCK; ++i)
            dst[i * BLOCK + threadIdx.x] = t[i];
        *reinterpret_cast<int4*>(&segl[4 * threadIdx.x])             = s0;
        *reinterpret_cast<int4*>(&segl[4 * (threadIdx.x + BLOCK)])   = s1;
        if (threadIdx.x == 0) segl[PIX_PER_BLOCK] = 0; // pad: speculative p+1
    }
    __syncthreads();

    float4* __restrict__ o =
        reinterpret_cast<float4*>(out) + (long long)blockIdx.x * F4_PER_BLOCK;

    #pragma unroll
    for (int q = 0; q < F4_PER_THR; ++q) {
        const unsigned gl  = q * BLOCK + threadIdx.x;   // block-local f4 idx
        const unsigned f   = 4u * gl;                   // block-local float idx
        const unsigned p   = f / 5u;                    // local pixel (magic-mul)
        const unsigned off = f - 5u * p;                // 0..4

        const int sa = segl[p];
        const int sb = segl[p + 1];
        const int r0 = sa * WAY;                        // row base, pixel p
        const int r1 = sb * WAY - 5;                    // row base, pixel p+1

        float4 x;
        float* xf = reinterpret_cast<float*>(&x);
        #pragma unroll
        for (int k = 0; k < 4; ++k) {
            const unsigned w = off + k;                 // 0..7
            const int idx = (w >= 5u ? r1 : r0) + (int)w;
            xf[k] = tab[idx];                           // ds_read_b32
        }
        o[gl] = x;                                      // coalesced 64x16B store
    }
}

extern "C" void kernel_launch(void* const* d_in, const int* in_sizes, int n_in,
                              void* d_out, int out_size, void* d_ws, size_t ws_size,
                              hipStream_t stream) {
    const float* logits = (const float*)d_in[0];
    const int*   seg    = (const int*)d_in[1];
    float*       out    = (float*)d_out;

    const int grid = N_IMG * BLOCKS_PER_IMG;   // 2048 blocks = 8/CU, one round
    gather5_direct2_kernel<<<grid, BLOCK, 0, stream>>>(logits, seg, out);
}